// Round 11
// baseline (335.748 us; speedup 1.0000x reference)
//
#include <hip/hip_runtime.h>

#define N 128
#define LSAP_INF 1e30f

// Uniform-lane readlane helpers (v_readlane_b32 with SGPR index).
__device__ __forceinline__ int rl_i(int v, int l) { return __builtin_amdgcn_readlane(v, l); }
__device__ __forceinline__ float rl_f(float v, int l) {
    return __int_as_float(__builtin_amdgcn_readlane(__float_as_int(v), l));
}
// Pick from the two 64-wide register slots by global index (0..127), uniform.
__device__ __forceinline__ int pick_i(int a0, int a1, int idx) {
    return (idx < 64) ? rl_i(a0, idx) : rl_i(a1, idx - 64);
}
__device__ __forceinline__ float pick_f(float a0, float a1, int idx) {
    return (idx < 64) ? rl_f(a0, idx) : rl_f(a1, idx - 64);
}
// Per-lane (non-uniform) gather from the two 64-wide slots via shuffles.
__device__ __forceinline__ float gather_f(float a0, float a1, int idx) {
    float x = __shfl(a0, idx & 63);
    float y = __shfl(a1, idx & 63);
    return (idx < 64) ? x : y;
}

// Wave64 (min, second-min) of u32 keys in ONE DPP butterfly. Each lane seeds
// with (min,max) of its two keys; combine is union-correct and lane 63's
// union chain is disjoint (shr 1/2/4/8 + bcast15 + bcast31), so m2 is the
// exact global second-min (keys are unique: low bits carry the column).
// The m-chain critical path equals the single-min version; the m2 ops fill
// parallel ILP slots (R9's mistake was a second SERIAL chain).
__device__ __forceinline__ void wave_min2_key(unsigned a, unsigned b,
                                              unsigned& m, unsigned& m2) {
    unsigned x = (a < b) ? a : b;
    unsigned y = (a < b) ? b : a;
#define DPP2(ctrl)                                                                      \
    {                                                                                   \
        unsigned ox = (unsigned)__builtin_amdgcn_update_dpp(                            \
            (int)0xFFFFFFFF, (int)x, (ctrl), 0xF, 0xF, false);                          \
        unsigned oy = (unsigned)__builtin_amdgcn_update_dpp(                            \
            (int)0xFFFFFFFF, (int)y, (ctrl), 0xF, 0xF, false);                          \
        unsigned mx = (x < ox) ? ox : x;                                                \
        x = (x < ox) ? x : ox;                                                          \
        y = (y < oy) ? y : oy;                                                          \
        y = (y < mx) ? y : mx;                                                          \
    }
    DPP2(0x111) DPP2(0x112) DPP2(0x114) DPP2(0x118) DPP2(0x142) DPP2(0x143)
#undef DPP2
    m  = (unsigned)rl_i((int)x, 63);
    m2 = (unsigned)rl_i((int)y, 63);
}

// min / argmin / second-min of reduced costs over both lane-owned rows.
// Diagonal scan j=(t+lane)&127: conflict-free (2-way aliasing only).
__device__ __forceinline__ void row_scan2(const float* Cs, const float* v_lds, int lane,
                                          float& m0, int& jm0, float& sm0,
                                          float& m1, int& jm1, float& sm1) {
    m0 = sm0 = m1 = sm1 = LSAP_INF;
    jm0 = jm1 = -1;
    for (int t = 0; t < N; ++t) {
        int j = (t + lane) & (N - 1);
        float vj = v_lds[j];
        float h0 = Cs[lane * N + j] - vj;
        float h1 = Cs[(lane + 64) * N + j] - vj;
        if (h0 < sm0) { if (h0 < m0) { sm0 = m0; m0 = h0; jm0 = j; } else sm0 = h0; }
        if (h1 < sm1) { if (h1 < m1) { sm1 = m1; m1 = h1; jm1 = j; } else sm1 = h1; }
    }
}

// One wave per batch. Lane L owns columns {L, L+64} and rows {L, L+64}.
__global__ __launch_bounds__(64) void lsap_kernel(const float* __restrict__ D,
                                                  float* __restrict__ out,
                                                  float inv) {
    const int b = blockIdx.x;
    const int lane = threadIdx.x;  // 0..63
    const float* __restrict__ C = D + (size_t)b * N * N;

    __shared__ float Cs[N * N];       // 65536 B
    __shared__ float v_lds[N];
    __shared__ float u_lds[N];
    __shared__ int rowsol_lds[N];     // row -> col (-1 free)
    __shared__ int colsol_lds[N];     // col -> row (-1 free)
    __shared__ int bid_lds[N];

    {
        const float4* __restrict__ src = (const float4*)C;
        float4* dst = (float4*)Cs;
#pragma unroll
        for (int t = 0; t < (N * N / 4) / 64; ++t) dst[t * 64 + lane] = src[t * 64 + lane];
    }
    __syncthreads();

    // ---- JV init phase 1: column reduction v[j] = min_i C[i][j] ----
    {
        float v0 = LSAP_INF, v1 = LSAP_INF;
        int am0 = -1, am1 = -1;
        for (int i = 0; i < N; ++i) {
            float c0 = Cs[i * N + lane];
            float c1 = Cs[i * N + lane + 64];
            if (c0 < v0) { v0 = c0; am0 = i; }
            if (c1 < v1) { v1 = c1; am1 = i; }
        }
        v_lds[lane] = v0;
        v_lds[lane + 64] = v1;
        rowsol_lds[lane] = -1; rowsol_lds[lane + 64] = -1;
        colsol_lds[lane] = -1; colsol_lds[lane + 64] = -1;
        __syncthreads();
        bid_lds[am0] = lane;
        bid_lds[am1] = lane + 64;
        __syncthreads();
        if (bid_lds[am0] == lane)      { colsol_lds[lane] = am0;      rowsol_lds[am0] = lane; }
        if (bid_lds[am1] == lane + 64) { colsol_lds[lane + 64] = am1; rowsol_lds[am1] = lane + 64; }
        __syncthreads();
    }

    // ---- JV init phase 2: reduction transfer; initialize u (row duals). ----
    {
        float m0, sm0, m1, sm1; int jm0, jm1;
        row_scan2(Cs, v_lds, lane, m0, jm0, sm0, m1, jm1, sm1);
        int j1_0 = rowsol_lds[lane];
        int j1_1 = rowsol_lds[lane + 64];
        __syncthreads();
        if (j1_0 >= 0) v_lds[j1_0] -= (sm0 - m0);   // distinct j1 per row
        if (j1_1 >= 0) v_lds[j1_1] -= (sm1 - m1);
        u_lds[lane]      = (j1_0 >= 0) ? sm0 : m0;
        u_lds[lane + 64] = (j1_1 >= 0) ? sm1 : m1;
        __syncthreads();
    }

    // ---- JV init phase 3: FORWARD-REVERSE Jacobi auction, eps = 0, cap 16
    // (measured optimum — R7/R10 showed both more rounds and a GS tail lose).
    // Invariants: (1) cbar = C-u-v >= 0; (2) assigned slack exactly 0. ----
    for (int round = 0; round < 16; ++round) {
        bool f0 = rowsol_lds[lane] < 0;
        bool f1 = rowsol_lds[lane + 64] < 0;
        if (__ballot(f0 || f1) == 0ULL) break;
        if ((round & 1) == 0) {
            float m0, sm0, m1, sm1; int jm0, jm1;
            row_scan2(Cs, v_lds, lane, m0, jm0, sm0, m1, jm1, sm1);
            bid_lds[lane] = -1;
            bid_lds[lane + 64] = -1;
            __syncthreads();
            if (f0) bid_lds[jm0] = lane;
            if (f1) bid_lds[jm1] = lane + 64;
            __syncthreads();
            if (f0 && bid_lds[jm0] == lane) {
                int old = colsol_lds[jm0];
                v_lds[jm0] -= (sm0 - m0);
                u_lds[lane] = sm0;
                colsol_lds[jm0] = lane;
                rowsol_lds[lane] = jm0;
                if (old >= 0) rowsol_lds[old] = -1;
            }
            if (f1 && bid_lds[jm1] == lane + 64) {
                int old = colsol_lds[jm1];
                v_lds[jm1] -= (sm1 - m1);
                u_lds[lane + 64] = sm1;
                colsol_lds[jm1] = lane + 64;
                rowsol_lds[lane + 64] = jm1;
                if (old >= 0) rowsol_lds[old] = -1;
            }
            __syncthreads();
        } else {
            bool g0 = colsol_lds[lane] < 0;
            bool g1 = colsol_lds[lane + 64] < 0;
            float m0 = LSAP_INF, sm0 = LSAP_INF, m1 = LSAP_INF, sm1 = LSAP_INF;
            int im0 = -1, im1 = -1;
            for (int t = 0; t < N; ++t) {
                int i = (t + lane) & (N - 1);
                float ui = u_lds[i];
                float y0 = Cs[i * N + lane] - ui;
                float y1 = Cs[i * N + lane + 64] - ui;
                if (y0 < sm0) { if (y0 < m0) { sm0 = m0; m0 = y0; im0 = i; } else sm0 = y0; }
                if (y1 < sm1) { if (y1 < m1) { sm1 = m1; m1 = y1; im1 = i; } else sm1 = y1; }
            }
            bid_lds[lane] = -1;
            bid_lds[lane + 64] = -1;
            __syncthreads();
            if (g0) bid_lds[im0] = lane;          // bid_lds indexed by ROW here
            if (g1) bid_lds[im1] = lane + 64;
            __syncthreads();
            if (g0 && bid_lds[im0] == lane) {
                float un = u_lds[im0] - (sm0 - m0);
                u_lds[im0] = un;
                v_lds[lane] = Cs[im0 * N + lane] - un;
                int oldc = rowsol_lds[im0];
                rowsol_lds[im0] = lane;
                colsol_lds[lane] = im0;
                if (oldc >= 0) colsol_lds[oldc] = -1;
            }
            if (g1 && bid_lds[im1] == lane + 64) {
                float un = u_lds[im1] - (sm1 - m1);
                u_lds[im1] = un;
                v_lds[lane + 64] = Cs[im1 * N + lane + 64] - un;
                int oldc = rowsol_lds[im1];
                rowsol_lds[im1] = lane + 64;
                colsol_lds[lane + 64] = im1;
                if (oldc >= 0) colsol_lds[oldc] = -1;
            }
            __syncthreads();
        }
    }

    // ---- Tighten u for free rows: u[i] = min_j (C[i][j] - v[j]). ----
    float umin0 = LSAP_INF, umin1 = LSAP_INF;
    for (int t = 0; t < N; ++t) {
        int j = (t + lane) & (N - 1);
        float vj = v_lds[j];
        umin0 = fminf(umin0, Cs[lane * N + j] - vj);
        umin1 = fminf(umin1, Cs[(lane + 64) * N + j] - vj);
    }

    // ---- Load solver state into registers ----
    float v0 = v_lds[lane], v1 = v_lds[lane + 64];
    int r4c0 = colsol_lds[lane], r4c1 = colsol_lds[lane + 64];
    int c4r0 = rowsol_lds[lane], c4r1 = rowsol_lds[lane + 64];
    float u0 = (c4r0 >= 0) ? u_lds[lane] : umin0;
    float u1 = (c4r1 >= 0) ? u_lds[lane + 64] : umin1;

    // Per-column cache of u[row4col[col]] (independent readlanes per pop).
    float urow0 = (r4c0 >= 0) ? gather_f(u0, u1, r4c0) : 0.f;
    float urow1 = (r4c1 >= 0) ? gather_f(u0, u1, r4c1) : 0.f;

    // ---- Exact phase: shortest augmenting path for each remaining free row.
    // Runner-up prefetch: the (min,min2) butterfly yields the next pop's
    // standing-min candidate j2 for free; its row/r4c/u are prefetched. On a
    // hit (next argmin == j2, common since relaxation only lowers keys), the
    // ~120cy LDS demand read and both readlanes leave the critical path. ----
    for (int cur = 0; cur < N; ++cur) {
        if (pick_i(c4r0, c4r1, cur) >= 0) continue;  // already assigned (uniform)

        float spc0 = LSAP_INF, spc1 = LSAP_INF;
        int path0 = -1, path1 = -1;
        bool rem0 = true, rem1 = true;
        bool sc0 = false, sc1 = false;
        bool sr0 = false, sr1 = false;
        int i = cur;                      // uniform
        float u_i = pick_f(u0, u1, i);
        float minVal = 0.f;
        int sink;
        // Carried row data + prefetch state (r4c frozen during a search).
        float c0 = Cs[i * N + lane];
        float c1 = Cs[i * N + lane + 64];
        int pj2 = -3, pi2 = 0;            // prev runner-up col / its row
        float pu2 = 0.f, pc0 = 0.f, pc1 = 0.f;

        while (true) {
            if (lane == (i & 63)) { if (i < 64) sr0 = true; else sr1 = true; }
            float base = minVal - u_i;
            // clamp vs float-rounding negatives (packed keys need >= 0)
            float r0 = fmaxf(base + c0 - v0, 0.f);
            float r1 = fmaxf(base + c1 - v1, 0.f);
            if (rem0 && (r0 < spc0)) { spc0 = r0; path0 = i; }
            if (rem1 && (r1 < spc1)) { spc1 = r1; path1 = i; }
            float m0c = rem0 ? spc0 : LSAP_INF;
            float m1c = rem1 ? spc1 : LSAP_INF;
            unsigned k0 = (((unsigned)__float_as_int(m0c)) & ~127u) | (unsigned)lane;
            unsigned k1 = (((unsigned)__float_as_int(m1c)) & ~127u) | (unsigned)(lane + 64);
            unsigned kmin, kmin2;
            wave_min2_key(k0, k1, kmin, kmin2);
            int j = (int)(kmin & 127u);              // wave-uniform argmin column
            minVal = __int_as_float((int)(kmin & ~127u));  // truncated (monotone)
            bool hit = (j == pj2);                   // uniform
            int rj    = hit ? pi2 : pick_i(r4c0, r4c1, j);
            float u_nx = hit ? pu2 : pick_f(urow0, urow1, j);
            if (lane == (j & 63)) {
                if (j < 64) { sc0 = true; rem0 = false; }
                else        { sc1 = true; rem1 = false; }
            }
            if (rj < 0) { sink = j; break; }
            // Row data for the next relax: prefetched (hit) or demand read.
            float nc0, nc1;
            if (hit) { nc0 = pc0; nc1 = pc1; }
            else     { nc0 = Cs[rj * N + lane]; nc1 = Cs[rj * N + lane + 64]; }
            // Prefetch the runner-up (= next pop's standing-min candidate).
            int j2 = (int)(kmin2 & 127u);
            if (kmin2 != 0xFFFFFFFFu) {
                pj2 = j2;
                int rj2 = pick_i(r4c0, r4c1, j2);
                pi2 = rj2;
                pu2 = pick_f(urow0, urow1, j2);
                int ra = (rj2 < 0) ? 0 : rj2;        // row unused if j2 is a sink
                pc0 = Cs[ra * N + lane];
                pc1 = Cs[ra * N + lane + 64];
            } else {
                pj2 = -3;
            }
            c0 = nc0; c1 = nc1;
            i = rj; u_i = u_nx;
        }

        // Dual updates
        {
            int g0i = (c4r0 < 0) ? 0 : c4r0;
            int g1i = (c4r1 < 0) ? 0 : c4r1;
            float g0 = gather_f(spc0, spc1, g0i);
            float g1 = gather_f(spc0, spc1, g1i);

            if (cur == lane)          u0 += minVal;
            else if (sr0)             u0 += minVal - g0;
            if (cur == lane + 64)     u1 += minVal;
            else if (sr1)             u1 += minVal - g1;
            if (sc0) v0 -= minVal - spc0;
            if (sc1) v1 -= minVal - spc1;
        }

        // Augment along alternating path
        int j = sink;
        while (true) {
            int ip = pick_i(path0, path1, j);   // uniform
            if (lane == (j & 63)) { if (j < 64) r4c0 = ip; else r4c1 = ip; }
            int jn = pick_i(c4r0, c4r1, ip);    // read BEFORE overwrite
            if (lane == (ip & 63)) { if (ip < 64) c4r0 = j; else c4r1 = j; }
            if (ip == cur) break;
            j = jn;
        }

        // Refresh per-column u-cache (u and r4c changed).
        urow0 = (r4c0 >= 0) ? gather_f(u0, u1, r4c0) : 0.f;
        urow1 = (r4c1 >= 0) ? gather_f(u0, u1, r4c1) : 0.f;
    }

    // Matched sum; fold the global mean into one device-scope atomic per block
    // (d_out zeroed via hipMemsetAsync).
    float s = Cs[lane * N + c4r0] + Cs[(lane + 64) * N + c4r1];
#pragma unroll
    for (int off = 32; off >= 1; off >>= 1) s += __shfl_xor(s, off);
    if (lane == 0) atomicAdd(out, s * inv);
}

extern "C" void kernel_launch(void* const* d_in, const int* in_sizes, int n_in,
                              void* d_out, int out_size, void* d_ws, size_t ws_size,
                              hipStream_t stream) {
    const float* D = (const float*)d_in[0];
    float* out = (float*)d_out;
    const int B = in_sizes[0] / (N * N);
    hipMemsetAsync(out, 0, sizeof(float), stream);
    lsap_kernel<<<B, 64, 0, stream>>>(D, out, 1.0f / (float)(B * N));
}

// Round 12
// 288.532 us; speedup vs baseline: 1.1636x; 1.1636x over previous
//
#include <hip/hip_runtime.h>

#define N 128
#define LSAP_INF 1e30f

// Uniform-lane readlane helpers (v_readlane_b32 with SGPR index).
__device__ __forceinline__ int rl_i(int v, int l) { return __builtin_amdgcn_readlane(v, l); }
__device__ __forceinline__ float rl_f(float v, int l) {
    return __int_as_float(__builtin_amdgcn_readlane(__float_as_int(v), l));
}
// Pick from the two 64-wide register slots by global index (0..127), uniform.
__device__ __forceinline__ int pick_i(int a0, int a1, int idx) {
    return (idx < 64) ? rl_i(a0, idx) : rl_i(a1, idx - 64);
}
__device__ __forceinline__ float pick_f(float a0, float a1, int idx) {
    return (idx < 64) ? rl_f(a0, idx) : rl_f(a1, idx - 64);
}
// Per-lane (non-uniform) gather from the two 64-wide slots via shuffles.
__device__ __forceinline__ float gather_f(float a0, float a1, int idx) {
    float x = __shfl(a0, idx & 63);
    float y = __shfl(a1, idx & 63);
    return (idx < 64) ? x : y;
}

// Wave64 min of a u32 key via DPP (VALU-only), broadcast via readlane 63.
// Single-min only: at 1 wave/CU every extra VALU instruction costs full issue
// latency (R11 post-mortem), so the butterfly must stay minimal.
__device__ __forceinline__ unsigned wave_min_key(unsigned x) {
#define DPP_STEP(ctrl)                                                                  \
    {                                                                                   \
        unsigned o = (unsigned)__builtin_amdgcn_update_dpp(                             \
            (int)0xFFFFFFFF, (int)x, (ctrl), 0xF, 0xF, false);                          \
        x = (o < x) ? o : x;                                                            \
    }
    DPP_STEP(0x111)  // row_shr:1
    DPP_STEP(0x112)  // row_shr:2
    DPP_STEP(0x114)  // row_shr:4
    DPP_STEP(0x118)  // row_shr:8
    DPP_STEP(0x142)  // row_bcast:15
    DPP_STEP(0x143)  // row_bcast:31
#undef DPP_STEP
    return (unsigned)rl_i((int)x, 63);
}

// min / argmin / second-min of reduced costs over both lane-owned rows.
// Diagonal scan j=(t+lane)&127: conflict-free (2-way aliasing only).
__device__ __forceinline__ void row_scan2(const float* Cs, const float* v_lds, int lane,
                                          float& m0, int& jm0, float& sm0,
                                          float& m1, int& jm1, float& sm1) {
    m0 = sm0 = m1 = sm1 = LSAP_INF;
    jm0 = jm1 = -1;
    for (int t = 0; t < N; ++t) {
        int j = (t + lane) & (N - 1);
        float vj = v_lds[j];
        float h0 = Cs[lane * N + j] - vj;
        float h1 = Cs[(lane + 64) * N + j] - vj;
        if (h0 < sm0) { if (h0 < m0) { sm0 = m0; m0 = h0; jm0 = j; } else sm0 = h0; }
        if (h1 < sm1) { if (h1 < m1) { sm1 = m1; m1 = h1; jm1 = j; } else sm1 = h1; }
    }
}

// One wave per batch. Lane L owns columns {L, L+64} and rows {L, L+64}.
__global__ __launch_bounds__(64) void lsap_kernel(const float* __restrict__ D,
                                                  float* __restrict__ out,
                                                  float inv) {
    const int b = blockIdx.x;
    const int lane = threadIdx.x;  // 0..63
    const float* __restrict__ C = D + (size_t)b * N * N;

    __shared__ float Cs[N * N];       // 65536 B
    __shared__ float v_lds[N];
    __shared__ float u_lds[N];
    __shared__ int rowsol_lds[N];     // row -> col (-1 free)
    __shared__ int colsol_lds[N];     // col -> row (-1 free)
    __shared__ int bid_lds[N];

    {
        const float4* __restrict__ src = (const float4*)C;
        float4* dst = (float4*)Cs;
#pragma unroll
        for (int t = 0; t < (N * N / 4) / 64; ++t) dst[t * 64 + lane] = src[t * 64 + lane];
    }
    __syncthreads();

    // ---- JV init phase 1: column reduction v[j] = min_i C[i][j] ----
    {
        float v0 = LSAP_INF, v1 = LSAP_INF;
        int am0 = -1, am1 = -1;
        for (int i = 0; i < N; ++i) {
            float c0 = Cs[i * N + lane];
            float c1 = Cs[i * N + lane + 64];
            if (c0 < v0) { v0 = c0; am0 = i; }
            if (c1 < v1) { v1 = c1; am1 = i; }
        }
        v_lds[lane] = v0;
        v_lds[lane + 64] = v1;
        rowsol_lds[lane] = -1; rowsol_lds[lane + 64] = -1;
        colsol_lds[lane] = -1; colsol_lds[lane + 64] = -1;
        __syncthreads();
        // column j claims its argmin row; LDS write race picks a valid winner
        bid_lds[am0] = lane;
        bid_lds[am1] = lane + 64;
        __syncthreads();
        if (bid_lds[am0] == lane)      { colsol_lds[lane] = am0;      rowsol_lds[am0] = lane; }
        if (bid_lds[am1] == lane + 64) { colsol_lds[lane + 64] = am1; rowsol_lds[am1] = lane + 64; }
        __syncthreads();
    }

    // ---- JV init phase 2: reduction transfer; initialize u (row duals). ----
    {
        float m0, sm0, m1, sm1; int jm0, jm1;
        row_scan2(Cs, v_lds, lane, m0, jm0, sm0, m1, jm1, sm1);
        int j1_0 = rowsol_lds[lane];
        int j1_1 = rowsol_lds[lane + 64];
        __syncthreads();
        if (j1_0 >= 0) v_lds[j1_0] -= (sm0 - m0);   // distinct j1 per row
        if (j1_1 >= 0) v_lds[j1_1] -= (sm1 - m1);
        u_lds[lane]      = (j1_0 >= 0) ? sm0 : m0;
        u_lds[lane + 64] = (j1_1 >= 0) ? sm1 : m1;
        __syncthreads();
    }

    // ---- JV init phase 3: FORWARD-REVERSE Jacobi auction, eps = 0, cap 16.
    // Measured optimum across R4/R7/R10/R11 variants. Invariants (both round
    // types, exact arithmetic):
    //   (1) cbar = C - u - v >= 0 everywhere
    //   (2) every assigned pair has slack exactly 0  ----
    for (int round = 0; round < 16; ++round) {
        bool f0 = rowsol_lds[lane] < 0;
        bool f1 = rowsol_lds[lane + 64] < 0;
        if (__ballot(f0 || f1) == 0ULL) break;
        if ((round & 1) == 0) {
            // FORWARD: free rows bid for columns
            float m0, sm0, m1, sm1; int jm0, jm1;
            row_scan2(Cs, v_lds, lane, m0, jm0, sm0, m1, jm1, sm1);
            bid_lds[lane] = -1;
            bid_lds[lane + 64] = -1;
            __syncthreads();
            if (f0) bid_lds[jm0] = lane;
            if (f1) bid_lds[jm1] = lane + 64;
            __syncthreads();
            if (f0 && bid_lds[jm0] == lane) {
                int old = colsol_lds[jm0];
                v_lds[jm0] -= (sm0 - m0);
                u_lds[lane] = sm0;
                colsol_lds[jm0] = lane;
                rowsol_lds[lane] = jm0;
                if (old >= 0) rowsol_lds[old] = -1;
            }
            if (f1 && bid_lds[jm1] == lane + 64) {
                int old = colsol_lds[jm1];
                v_lds[jm1] -= (sm1 - m1);
                u_lds[lane + 64] = sm1;
                colsol_lds[jm1] = lane + 64;
                rowsol_lds[lane + 64] = jm1;
                if (old >= 0) rowsol_lds[old] = -1;
            }
            __syncthreads();
        } else {
            // REVERSE: free columns bid for rows over y_i = C[i][j] - u[i].
            bool g0 = colsol_lds[lane] < 0;
            bool g1 = colsol_lds[lane + 64] < 0;
            float m0 = LSAP_INF, sm0 = LSAP_INF, m1 = LSAP_INF, sm1 = LSAP_INF;
            int im0 = -1, im1 = -1;
            for (int t = 0; t < N; ++t) {
                int i = (t + lane) & (N - 1);
                float ui = u_lds[i];
                float y0 = Cs[i * N + lane] - ui;
                float y1 = Cs[i * N + lane + 64] - ui;
                if (y0 < sm0) { if (y0 < m0) { sm0 = m0; m0 = y0; im0 = i; } else sm0 = y0; }
                if (y1 < sm1) { if (y1 < m1) { sm1 = m1; m1 = y1; im1 = i; } else sm1 = y1; }
            }
            bid_lds[lane] = -1;
            bid_lds[lane + 64] = -1;
            __syncthreads();
            if (g0) bid_lds[im0] = lane;          // bid_lds indexed by ROW here
            if (g1) bid_lds[im1] = lane + 64;
            __syncthreads();
            if (g0 && bid_lds[im0] == lane) {
                float un = u_lds[im0] - (sm0 - m0);
                u_lds[im0] = un;
                v_lds[lane] = Cs[im0 * N + lane] - un;
                int oldc = rowsol_lds[im0];
                rowsol_lds[im0] = lane;
                colsol_lds[lane] = im0;
                if (oldc >= 0) colsol_lds[oldc] = -1;
            }
            if (g1 && bid_lds[im1] == lane + 64) {
                float un = u_lds[im1] - (sm1 - m1);
                u_lds[im1] = un;
                v_lds[lane + 64] = Cs[im1 * N + lane + 64] - un;
                int oldc = rowsol_lds[im1];
                rowsol_lds[im1] = lane + 64;
                colsol_lds[lane + 64] = im1;
                if (oldc >= 0) colsol_lds[oldc] = -1;
            }
            __syncthreads();
        }
    }

    // ---- Tighten u for free rows: u[i] = min_j (C[i][j] - v[j]). ----
    float umin0 = LSAP_INF, umin1 = LSAP_INF;
    for (int t = 0; t < N; ++t) {
        int j = (t + lane) & (N - 1);
        float vj = v_lds[j];
        umin0 = fminf(umin0, Cs[lane * N + j] - vj);
        umin1 = fminf(umin1, Cs[(lane + 64) * N + j] - vj);
    }

    // ---- Load solver state into registers ----
    float v0 = v_lds[lane], v1 = v_lds[lane + 64];
    int r4c0 = colsol_lds[lane], r4c1 = colsol_lds[lane + 64];
    int c4r0 = rowsol_lds[lane], c4r1 = rowsol_lds[lane + 64];
    float u0 = (c4r0 >= 0) ? u_lds[lane] : umin0;
    float u1 = (c4r1 >= 0) ? u_lds[lane + 64] : umin1;

    // Per-column cache of u[row4col[col]] — lets the pop fetch rj and u[rj]
    // with two INDEPENDENT readlanes. Regathered once per augment.
    float urow0 = (r4c0 >= 0) ? gather_f(u0, u1, r4c0) : 0.f;
    float urow1 = (r4c1 >= 0) ? gather_f(u0, u1, r4c1) : 0.f;

    // ---- Exact phase: shortest augmenting path for each remaining free row ----
    for (int cur = 0; cur < N; ++cur) {
        if (pick_i(c4r0, c4r1, cur) >= 0) continue;  // already assigned (uniform)

        float spc0 = LSAP_INF, spc1 = LSAP_INF;
        int path0 = -1, path1 = -1;
        bool rem0 = true, rem1 = true;
        bool sc0 = false, sc1 = false;
        bool sr0 = false, sr1 = false;
        int i = cur;                      // uniform
        float u_i = pick_f(u0, u1, i);
        float minVal = 0.f;
        int sink;

        while (true) {
            if (lane == (i & 63)) { if (i < 64) sr0 = true; else sr1 = true; }
            float c0 = Cs[i * N + lane];
            float c1 = Cs[i * N + lane + 64];
            float base = minVal - u_i;
            // clamp vs float-rounding negatives: true reduced path costs >= 0,
            // and the packed-key argmin below needs non-negative floats.
            float r0 = fmaxf(base + c0 - v0, 0.f);
            float r1 = fmaxf(base + c1 - v1, 0.f);
            if (rem0 && (r0 < spc0)) { spc0 = r0; path0 = i; }
            if (rem1 && (r1 < spc1)) { spc1 = r1; path1 = i; }
            float m0c = rem0 ? spc0 : LSAP_INF;
            float m1c = rem1 ? spc1 : LSAP_INF;
            // Packed-key argmin: non-negative float bits are int-orderable.
            // Low 7 bits carry the column index. minVal uses the TRUNCATED
            // key value (<= true by 2^-17 relative; monotone; saves the
            // exact-value readlane — objective error ~1e-5 vs 4.9e-2 thresh).
            unsigned k0 = (((unsigned)__float_as_int(m0c)) & ~127u) | (unsigned)lane;
            unsigned k1 = (((unsigned)__float_as_int(m1c)) & ~127u) | (unsigned)(lane + 64);
            unsigned kmin = wave_min_key((k0 < k1) ? k0 : k1);
            int j = (int)(kmin & 127u);              // wave-uniform argmin column
            minVal = __int_as_float((int)(kmin & ~127u));
            int rj = pick_i(r4c0, r4c1, j);          // independent readlanes off j
            float u_next = pick_f(urow0, urow1, j);
            if (lane == (j & 63)) {
                if (j < 64) { sc0 = true; rem0 = false; }
                else        { sc1 = true; rem1 = false; }
            }
            if (rj < 0) { sink = j; break; }
            i = rj;
            u_i = u_next;
        }

        // Dual updates
        {
            int g0i = (c4r0 < 0) ? 0 : c4r0;
            int g1i = (c4r1 < 0) ? 0 : c4r1;
            float g0 = gather_f(spc0, spc1, g0i);
            float g1 = gather_f(spc0, spc1, g1i);

            if (cur == lane)          u0 += minVal;
            else if (sr0)             u0 += minVal - g0;
            if (cur == lane + 64)     u1 += minVal;
            else if (sr1)             u1 += minVal - g1;
            if (sc0) v0 -= minVal - spc0;
            if (sc1) v1 -= minVal - spc1;
        }

        // Augment along alternating path
        int j = sink;
        while (true) {
            int ip = pick_i(path0, path1, j);   // uniform
            if (lane == (j & 63)) { if (j < 64) r4c0 = ip; else r4c1 = ip; }
            int jn = pick_i(c4r0, c4r1, ip);    // read BEFORE overwrite
            if (lane == (ip & 63)) { if (ip < 64) c4r0 = j; else c4r1 = j; }
            if (ip == cur) break;
            j = jn;
        }

        // Refresh per-column u-cache (u and r4c changed).
        urow0 = (r4c0 >= 0) ? gather_f(u0, u1, r4c0) : 0.f;
        urow1 = (r4c1 >= 0) ? gather_f(u0, u1, r4c1) : 0.f;
    }

    // Matched sum; fold the global mean into one device-scope atomic per block
    // (d_out zeroed via hipMemsetAsync).
    float s = Cs[lane * N + c4r0] + Cs[(lane + 64) * N + c4r1];
#pragma unroll
    for (int off = 32; off >= 1; off >>= 1) s += __shfl_xor(s, off);
    if (lane == 0) atomicAdd(out, s * inv);
}

extern "C" void kernel_launch(void* const* d_in, const int* in_sizes, int n_in,
                              void* d_out, int out_size, void* d_ws, size_t ws_size,
                              hipStream_t stream) {
    const float* D = (const float*)d_in[0];
    float* out = (float*)d_out;
    const int B = in_sizes[0] / (N * N);
    hipMemsetAsync(out, 0, sizeof(float), stream);
    lsap_kernel<<<B, 64, 0, stream>>>(D, out, 1.0f / (float)(B * N));
}